// Round 1
// baseline (220.474 us; speedup 1.0000x reference)
//
#include <hip/hip_runtime.h>
#include <hip/hip_bf16.h>

// Problem constants: B=2, N=2048, D=1024, H=16, DH=64
namespace {

typedef short short8 __attribute__((ext_vector_type(8)));
typedef float f32x4 __attribute__((ext_vector_type(4)));

__device__ __forceinline__ unsigned short f2bf(float f) {
  union { __hip_bfloat16 h; unsigned short u; } cv;
  cv.h = __float2bfloat16(f);
  return cv.u;
}

// async global->LDS, 16B per lane. LDS ptr must be wave-uniform (lane l lands at +l*16).
__device__ __forceinline__ void load_lds16(const void* g, void* l) {
  __builtin_amdgcn_global_load_lds((__attribute__((address_space(1))) void*)g,
                                   (__attribute__((address_space(3))) void*)l,
                                   16, 0, 0);
}

// ---------------- fp32 -> bf16 convert ----------------
__global__ __launch_bounds__(256) void cvt_f32_bf16(const float4* __restrict__ in,
                                                    ushort4* __restrict__ out, int n4) {
  int i = blockIdx.x * 256 + threadIdx.x;
  if (i < n4) {
    float4 f = in[i];
    ushort4 u;
    u.x = f2bf(f.x); u.y = f2bf(f.y); u.z = f2bf(f.z); u.w = f2bf(f.w);
    out[i] = u;
  }
}

// ---------------- GEMM1: qkv = x @ Wqkv^T, scatter to q/k/vT ----------------
// Xb [4096][1024] bf16, Wb [3072][1024] bf16 (rows are outputs -> B^T GEMM)
// q,k -> [B*H][N][64]; v -> transposed [B*H][64][N]
__global__ __launch_bounds__(256) void gemm_qkv(const unsigned short* __restrict__ Xb,
                                                const unsigned short* __restrict__ Wb,
                                                unsigned short* __restrict__ qws,
                                                unsigned short* __restrict__ kws,
                                                unsigned short* __restrict__ vTws) {
  __shared__ unsigned short lA[128 * 32];
  __shared__ unsigned short lB[128 * 32];
  const int t = threadIdx.x;
  const int w = t >> 6, l = t & 63;
  const int wm = w >> 1, wn = w & 1;
  const int row0 = blockIdx.x * 128, col0 = blockIdx.y * 128;
  f32x4 acc[4][4] = {};
  for (int k0 = 0; k0 < 1024; k0 += 32) {
    __syncthreads();
#pragma unroll
    for (int i = 0; i < 2; ++i) {
      load_lds16(Xb + (size_t)(row0 + i * 64 + (t >> 2)) * 1024 + k0 + (t & 3) * 8,
                 &lA[i * 2048 + w * 512]);
      load_lds16(Wb + (size_t)(col0 + i * 64 + (t >> 2)) * 1024 + k0 + (t & 3) * 8,
                 &lB[i * 2048 + w * 512]);
    }
    __syncthreads();
    short8 af[4], bf[4];
#pragma unroll
    for (int mi = 0; mi < 4; ++mi)
      af[mi] = *(const short8*)&lA[(wm * 64 + mi * 16 + (l & 15)) * 32 + (l >> 4) * 8];
#pragma unroll
    for (int ni = 0; ni < 4; ++ni)
      bf[ni] = *(const short8*)&lB[(wn * 64 + ni * 16 + (l & 15)) * 32 + (l >> 4) * 8];
#pragma unroll
    for (int mi = 0; mi < 4; ++mi)
#pragma unroll
      for (int ni = 0; ni < 4; ++ni)
        acc[mi][ni] = __builtin_amdgcn_mfma_f32_16x16x32_bf16(af[mi], bf[ni], acc[mi][ni], 0, 0, 0);
  }
#pragma unroll
  for (int mi = 0; mi < 4; ++mi)
#pragma unroll
    for (int ni = 0; ni < 4; ++ni)
#pragma unroll
      for (int r = 0; r < 4; ++r) {
        int row = row0 + wm * 64 + mi * 16 + (l >> 4) * 4 + r;
        int col = col0 + wn * 64 + ni * 16 + (l & 15);
        int b = row >> 11, n = row & 2047;
        int s = col >> 10, rem = col & 1023;
        int h = rem >> 6, dh = rem & 63;
        unsigned short u = f2bf(acc[mi][ni][r]);
        size_t bh = (size_t)(b * 16 + h);
        if (s == 0)      qws[(bh * 2048 + n) * 64 + dh] = u;
        else if (s == 1) kws[(bh * 2048 + n) * 64 + dh] = u;
        else             vTws[(bh * 64 + dh) * 2048 + n] = u;
      }
}

// ---------------- Flash attention ----------------
// grid (N/64, H, B), 256 thr (4 waves x 16 q-rows). K-tile = 64 keys.
__global__ __launch_bounds__(256) void attn_fwd(const unsigned short* __restrict__ qws,
                                                const unsigned short* __restrict__ kws,
                                                const unsigned short* __restrict__ vTws,
                                                const float* __restrict__ bias,
                                                const int* __restrict__ mask,
                                                unsigned short* __restrict__ ctx) {
  __shared__ unsigned short lK[64 * 64];
  __shared__ unsigned short lVT[64 * 64];
  __shared__ unsigned short lP[4 * 16 * 64];
  const int t = threadIdx.x, w = t >> 6, l = t & 63;
  const int qt = blockIdx.x, h = blockIdx.y, b = blockIdx.z;
  const size_t bh = (size_t)(b * 16 + h);
  const unsigned short* Q = qws + bh * 2048 * 64;
  const unsigned short* K = kws + bh * 2048 * 64;
  const unsigned short* VT = vTws + bh * 64 * 2048;
  const float* brow = bias + (size_t)b * 2048 * 2048;
  const int* mrow = mask + b * 2048;
  const int qrow = qt * 64 + w * 16 + (l & 15);
  short8 qf[2];
  qf[0] = *(const short8*)&Q[(size_t)qrow * 64 + (l >> 4) * 8];
  qf[1] = *(const short8*)&Q[(size_t)qrow * 64 + 32 + (l >> 4) * 8];
  int qg[4];
#pragma unroll
  for (int r = 0; r < 4; ++r) qg[r] = qt * 64 + w * 16 + (l >> 4) * 4 + r;
  float m[4], lsum[4];
  f32x4 o[4] = {};
#pragma unroll
  for (int r = 0; r < 4; ++r) { m[r] = -INFINITY; lsum[r] = 0.f; }
  unsigned short* myP = &lP[w * 1024];

  for (int kt = 0; kt < 2048; kt += 64) {
    __syncthreads();
#pragma unroll
    for (int i = 0; i < 2; ++i) {
      load_lds16(K + (size_t)(kt + i * 32 + (t >> 3)) * 64 + (t & 7) * 8,
                 &lK[i * 2048 + w * 512]);
      load_lds16(VT + (size_t)(i * 32 + (t >> 3)) * 2048 + kt + (t & 7) * 8,
                 &lVT[i * 2048 + w * 512]);
    }
    __syncthreads();

    // S = Q K^T  (per wave: 16 q-rows x 64 keys, 4 key-subtiles of 16)
    f32x4 s4[4];
#pragma unroll
    for (int j = 0; j < 4; ++j) {
      f32x4 sj = {0.f, 0.f, 0.f, 0.f};
      short8 kf0 = *(const short8*)&lK[(j * 16 + (l & 15)) * 64 + (l >> 4) * 8];
      short8 kf1 = *(const short8*)&lK[(j * 16 + (l & 15)) * 64 + 32 + (l >> 4) * 8];
      sj = __builtin_amdgcn_mfma_f32_16x16x32_bf16(qf[0], kf0, sj, 0, 0, 0);
      sj = __builtin_amdgcn_mfma_f32_16x16x32_bf16(qf[1], kf1, sj, 0, 0, 0);
      s4[j] = sj;
    }
    // scale + bias + key-padding mask; row max
    float rmax[4];
#pragma unroll
    for (int r = 0; r < 4; ++r) rmax[r] = -1e30f;
#pragma unroll
    for (int j = 0; j < 4; ++j) {
      const int key = kt + j * 16 + (l & 15);
      const bool keep = mrow[key] != 0;
#pragma unroll
      for (int r = 0; r < 4; ++r) {
        float sv = s4[j][r] * 0.125f + brow[(size_t)qg[r] * 2048 + key];
        sv = keep ? sv : -1e30f;
        s4[j][r] = sv;
        rmax[r] = fmaxf(rmax[r], sv);
      }
    }
#pragma unroll
    for (int d = 1; d < 16; d <<= 1)
#pragma unroll
      for (int r = 0; r < 4; ++r) rmax[r] = fmaxf(rmax[r], __shfl_xor(rmax[r], d, 64));
    // online softmax update
    float alpha[4];
#pragma unroll
    for (int r = 0; r < 4; ++r) {
      float mn = fmaxf(m[r], rmax[r]);
      alpha[r] = __expf(m[r] - mn);  // exp(-inf - finite) = 0 on first tile
      m[r] = mn;
    }
    float rsum[4] = {0.f, 0.f, 0.f, 0.f};
#pragma unroll
    for (int j = 0; j < 4; ++j)
#pragma unroll
      for (int r = 0; r < 4; ++r) {
        float p = __expf(s4[j][r] - m[r]);
        s4[j][r] = p;
        rsum[r] += p;
      }
#pragma unroll
    for (int d = 1; d < 16; d <<= 1)
#pragma unroll
      for (int r = 0; r < 4; ++r) rsum[r] += __shfl_xor(rsum[r], d, 64);
#pragma unroll
    for (int r = 0; r < 4; ++r) lsum[r] = lsum[r] * alpha[r] + rsum[r];
#pragma unroll
    for (int ni = 0; ni < 4; ++ni)
#pragma unroll
      for (int r = 0; r < 4; ++r) o[ni][r] *= alpha[r];
    // P (C-layout) -> LDS -> A-fragment layout for PV
#pragma unroll
    for (int j = 0; j < 4; ++j)
#pragma unroll
      for (int r = 0; r < 4; ++r)
        myP[((l >> 4) * 4 + r) * 64 + j * 16 + (l & 15)] = f2bf(s4[j][r]);
#pragma unroll
    for (int c = 0; c < 2; ++c) {
      short8 pf = *(const short8*)&myP[(l & 15) * 64 + c * 32 + (l >> 4) * 8];
#pragma unroll
      for (int ni = 0; ni < 4; ++ni) {
        short8 vf = *(const short8*)&lVT[(ni * 16 + (l & 15)) * 64 + c * 32 + (l >> 4) * 8];
        o[ni] = __builtin_amdgcn_mfma_f32_16x16x32_bf16(pf, vf, o[ni], 0, 0, 0);
      }
    }
  }
#pragma unroll
  for (int r = 0; r < 4; ++r) {
    float inv = 1.0f / lsum[r];
#pragma unroll
    for (int ni = 0; ni < 4; ++ni)
      ctx[((size_t)b * 2048 + qg[r]) * 1024 + h * 64 + ni * 16 + (l & 15)] =
          f2bf(o[ni][r] * inv);
  }
}

// ---------------- GEMM2: out = ctx @ Wproj^T + bproj (fp32 out) ----------------
__global__ __launch_bounds__(256) void gemm_proj(const unsigned short* __restrict__ Cb,
                                                 const unsigned short* __restrict__ Wb,
                                                 const float* __restrict__ bproj,
                                                 float* __restrict__ out) {
  __shared__ unsigned short lA[128 * 32];
  __shared__ unsigned short lB[128 * 32];
  const int t = threadIdx.x;
  const int w = t >> 6, l = t & 63;
  const int wm = w >> 1, wn = w & 1;
  const int row0 = blockIdx.x * 128, col0 = blockIdx.y * 128;
  f32x4 acc[4][4] = {};
  for (int k0 = 0; k0 < 1024; k0 += 32) {
    __syncthreads();
#pragma unroll
    for (int i = 0; i < 2; ++i) {
      load_lds16(Cb + (size_t)(row0 + i * 64 + (t >> 2)) * 1024 + k0 + (t & 3) * 8,
                 &lA[i * 2048 + w * 512]);
      load_lds16(Wb + (size_t)(col0 + i * 64 + (t >> 2)) * 1024 + k0 + (t & 3) * 8,
                 &lB[i * 2048 + w * 512]);
    }
    __syncthreads();
    short8 af[4], bf[4];
#pragma unroll
    for (int mi = 0; mi < 4; ++mi)
      af[mi] = *(const short8*)&lA[(wm * 64 + mi * 16 + (l & 15)) * 32 + (l >> 4) * 8];
#pragma unroll
    for (int ni = 0; ni < 4; ++ni)
      bf[ni] = *(const short8*)&lB[(wn * 64 + ni * 16 + (l & 15)) * 32 + (l >> 4) * 8];
#pragma unroll
    for (int mi = 0; mi < 4; ++mi)
#pragma unroll
      for (int ni = 0; ni < 4; ++ni)
        acc[mi][ni] = __builtin_amdgcn_mfma_f32_16x16x32_bf16(af[mi], bf[ni], acc[mi][ni], 0, 0, 0);
  }
#pragma unroll
  for (int mi = 0; mi < 4; ++mi)
#pragma unroll
    for (int ni = 0; ni < 4; ++ni)
#pragma unroll
      for (int r = 0; r < 4; ++r) {
        int row = row0 + wm * 64 + mi * 16 + (l >> 4) * 4 + r;
        int col = col0 + wn * 64 + ni * 16 + (l & 15);
        out[(size_t)row * 1024 + col] = acc[mi][ni][r] + bproj[col];
      }
}

}  // namespace

extern "C" void kernel_launch(void* const* d_in, const int* in_sizes, int n_in,
                              void* d_out, int out_size, void* d_ws, size_t ws_size,
                              hipStream_t stream) {
  (void)in_sizes; (void)n_in; (void)out_size; (void)ws_size;
  const float* x        = (const float*)d_in[0];   // [2,2048,1024]
  const float* attnbias = (const float*)d_in[1];   // [2,2048,2048]
  const int*   mask     = (const int*)d_in[2];     // [2,2048] (bool -> int32)
  const float* Wqkv     = (const float*)d_in[3];   // [3072,1024]
  const float* Wproj    = (const float*)d_in[4];   // [1024,1024]
  const float* bproj    = (const float*)d_in[5];   // [1024]
  float* out = (float*)d_out;

  unsigned short* ws     = (unsigned short*)d_ws;
  unsigned short* xb     = ws;                  // 4194304 bf16
  unsigned short* wqkvb  = xb + 4194304;        // 3145728
  unsigned short* wprojb = wqkvb + 3145728;     // 1048576
  unsigned short* qws    = wprojb + 1048576;    // 4194304  [B*H][N][64]
  unsigned short* kws    = qws + 4194304;       // 4194304  [B*H][N][64]
  unsigned short* vTws   = kws + 4194304;       // 4194304  [B*H][64][N]
  unsigned short* ctxb   = vTws + 4194304;      // 4194304  [B][N][D]
  // total ws use: 48 MiB

  cvt_f32_bf16<<<4096, 256, 0, stream>>>((const float4*)x,     (ushort4*)xb,     1048576);
  cvt_f32_bf16<<<3072, 256, 0, stream>>>((const float4*)Wqkv,  (ushort4*)wqkvb,  786432);
  cvt_f32_bf16<<<1024, 256, 0, stream>>>((const float4*)Wproj, (ushort4*)wprojb, 262144);
  gemm_qkv<<<dim3(32, 24), 256, 0, stream>>>(xb, wqkvb, qws, kws, vTws);
  attn_fwd<<<dim3(32, 16, 2), 256, 0, stream>>>(qws, kws, vTws, attnbias, mask, ctxb);
  gemm_proj<<<dim3(32, 8), 256, 0, stream>>>(ctxb, wprojb, bproj, out);
}

// Round 2
// 191.183 us; speedup vs baseline: 1.1532x; 1.1532x over previous
//
#include <hip/hip_runtime.h>
#include <hip/hip_bf16.h>

// Problem constants: B=2, N=2048, D=1024, H=16, DH=64
namespace {

typedef short short8 __attribute__((ext_vector_type(8)));
typedef float f32x4 __attribute__((ext_vector_type(4)));

__device__ __forceinline__ unsigned short f2bf(float f) {
  union { __hip_bfloat16 h; unsigned short u; } cv;
  cv.h = __float2bfloat16(f);
  return cv.u;
}

// async global->LDS, 16B per lane. LDS base must be wave-uniform (lane l lands at +l*16B).
__device__ __forceinline__ void load_lds16(const void* g, void* l) {
  __builtin_amdgcn_global_load_lds((__attribute__((address_space(1))) void*)g,
                                   (__attribute__((address_space(3))) void*)l,
                                   16, 0, 0);
}

// ---------------- fp32 -> bf16 convert (all three tensors, one launch) ----------
__global__ __launch_bounds__(256) void cvt_all(const float4* __restrict__ x,
                                               const float4* __restrict__ wqkv,
                                               const float4* __restrict__ wproj,
                                               ushort4* __restrict__ xb,
                                               ushort4* __restrict__ wqkvb,
                                               ushort4* __restrict__ wprojb) {
  int i = blockIdx.x * 256 + threadIdx.x;
  const float4* src;
  ushort4* dst;
  int off;
  if (i < 1048576) { src = x; dst = xb; off = i; }
  else if (i < 1048576 + 786432) { src = wqkv; dst = wqkvb; off = i - 1048576; }
  else { src = wproj; dst = wprojb; off = i - (1048576 + 786432); }
  float4 f = src[off];
  ushort4 u;
  u.x = f2bf(f.x); u.y = f2bf(f.y); u.z = f2bf(f.z); u.w = f2bf(f.w);
  dst[off] = u;
}

// ---------------- GEMM1: qkv = x @ Wqkv^T, scatter to q/k/vT ----------------
// Xb [4096][1024] bf16, Wb [3072][1024] bf16. q,k -> [B*H][N][64]; v -> [B*H][64][N]
// LDS tiles [128 rows][32 k] bf16, rows = 4 chunks of 16B, XOR-swizzled slot = chunk ^ (row&3).
__global__ __launch_bounds__(256) void gemm_qkv(const unsigned short* __restrict__ Xb,
                                                const unsigned short* __restrict__ Wb,
                                                unsigned short* __restrict__ qws,
                                                unsigned short* __restrict__ kws,
                                                unsigned short* __restrict__ vTws) {
  __shared__ unsigned short lA[128 * 32];
  __shared__ unsigned short lB[128 * 32];
  const int t = threadIdx.x;
  const int w = t >> 6, l = t & 63;
  const int wm = w >> 1, wn = w & 1;
  const int lr = l & 15, lg = l >> 4;
  const int row0 = blockIdx.x * 128, col0 = blockIdx.y * 128;
  const int srow = t >> 2;                       // staging row 0..63 (+64 for i=1)
  const int schunk = (t & 3) ^ (srow & 3);       // inverse-swizzled source chunk
  f32x4 acc[4][4] = {};
  for (int k0 = 0; k0 < 1024; k0 += 32) {
    __syncthreads();
    load_lds16(Xb + (size_t)(row0 + srow) * 1024 + k0 + schunk * 8, &lA[w * 512]);
    load_lds16(Xb + (size_t)(row0 + 64 + srow) * 1024 + k0 + schunk * 8, &lA[2048 + w * 512]);
    load_lds16(Wb + (size_t)(col0 + srow) * 1024 + k0 + schunk * 8, &lB[w * 512]);
    load_lds16(Wb + (size_t)(col0 + 64 + srow) * 1024 + k0 + schunk * 8, &lB[2048 + w * 512]);
    __syncthreads();
    short8 af[4], bf[4];
    const int rslot = (lg ^ (l & 3)) * 8;
#pragma unroll
    for (int mi = 0; mi < 4; ++mi)
      af[mi] = *(const short8*)&lA[(wm * 64 + mi * 16 + lr) * 32 + rslot];
#pragma unroll
    for (int ni = 0; ni < 4; ++ni)
      bf[ni] = *(const short8*)&lB[(wn * 64 + ni * 16 + lr) * 32 + rslot];
#pragma unroll
    for (int mi = 0; mi < 4; ++mi)
#pragma unroll
      for (int ni = 0; ni < 4; ++ni)
        acc[mi][ni] = __builtin_amdgcn_mfma_f32_16x16x32_bf16(af[mi], bf[ni], acc[mi][ni], 0, 0, 0);
  }
#pragma unroll
  for (int mi = 0; mi < 4; ++mi)
#pragma unroll
    for (int ni = 0; ni < 4; ++ni) {
      const int col = col0 + wn * 64 + ni * 16 + lr;
      const int s = col >> 10, rem = col & 1023;
      const int hh = rem >> 6, dh = rem & 63;
      const int row = row0 + wm * 64 + mi * 16 + lg * 4;
      const int bb = row >> 11, n = row & 2047;
      const size_t bh = (size_t)(bb * 16 + hh);
      if (s == 2) {
        ushort4 u4;
        u4.x = f2bf(acc[mi][ni][0]); u4.y = f2bf(acc[mi][ni][1]);
        u4.z = f2bf(acc[mi][ni][2]); u4.w = f2bf(acc[mi][ni][3]);
        *(ushort4*)&vTws[(bh * 64 + dh) * 2048 + n] = u4;
      } else {
        unsigned short* dst = (s == 0) ? qws : kws;
#pragma unroll
        for (int r = 0; r < 4; ++r)
          dst[(bh * 2048 + n + r) * 64 + dh] = f2bf(acc[mi][ni][r]);
      }
    }
}

// ---------------- Flash attention ----------------
// grid (N/64, H, B), 256 thr (4 waves x 16 q-rows). K-tile = 64 keys.
// lK/lVT: [64 rows][64 cols] bf16 (8 chunks of 16B per row), slot = chunk ^ (row&7),
// staged via inverse-swizzled global source (LDS dest stays linear).
__global__ __launch_bounds__(256) void attn_fwd(const unsigned short* __restrict__ qws,
                                                const unsigned short* __restrict__ kws,
                                                const unsigned short* __restrict__ vTws,
                                                const float* __restrict__ bias,
                                                const int* __restrict__ mask,
                                                unsigned short* __restrict__ ctx) {
  __shared__ unsigned short lK[64 * 64];
  __shared__ unsigned short lVT[64 * 64];
  __shared__ unsigned short lP[4 * 16 * 64];
  __shared__ int lred[4];
  const int t = threadIdx.x, w = t >> 6, l = t & 63;
  const int lr = l & 15, lg = l >> 4;
  const int qt = blockIdx.x, h = blockIdx.y, b = blockIdx.z;
  const size_t bh = (size_t)(b * 16 + h);
  const unsigned short* Q = qws + bh * (2048 * 64);
  const unsigned short* K = kws + bh * (2048 * 64);
  const unsigned short* VT = vTws + bh * (64 * 2048);
  const float* brow = bias + (size_t)b * (2048 * 2048);

  // ---- sequence length for this batch (prefix mask -> popcount) ----
  const int* mrow = mask + b * 2048;
  int scnt = 0;
  for (int i = t; i < 2048; i += 256) scnt += (mrow[i] != 0);
#pragma unroll
  for (int d = 1; d < 64; d <<= 1) scnt += __shfl_xor(scnt, d, 64);
  if (l == 0) lred[w] = scnt;
  __syncthreads();
  const int len = lred[0] + lred[1] + lred[2] + lred[3];
  const int nt = (len + 63) >> 6;

  const int qrow = qt * 64 + w * 16 + lr;
  short8 qf[2];
  qf[0] = *(const short8*)&Q[(size_t)qrow * 64 + lg * 8];
  qf[1] = *(const short8*)&Q[(size_t)qrow * 64 + 32 + lg * 8];
  size_t qoff[4];
#pragma unroll
  for (int r = 0; r < 4; ++r)
    qoff[r] = (size_t)(qt * 64 + w * 16 + lg * 4 + r) * 2048;

  float m[4], lsum[4];
  f32x4 o[4] = {};
#pragma unroll
  for (int r = 0; r < 4; ++r) { m[r] = -INFINITY; lsum[r] = 0.f; }
  unsigned short* myP = &lP[w * 1024];

  // staging geometry: thread t covers LDS row srow (srow+32 for 2nd inst), chunk slot t&7
  const int srow = t >> 3;
  const int schunk = (t & 7) ^ (srow & 7);
  const int xr7 = (l & 7);  // row&7 for all fragment reads (rows = k*16 + lr)

  for (int kt_i = 0; kt_i < nt; ++kt_i) {
    const int kt = kt_i << 6;
    __syncthreads();
    // bias loads issued first: latency hides under the LDS staging drain
    float bfv[4][4];
#pragma unroll
    for (int j = 0; j < 4; ++j)
#pragma unroll
      for (int r = 0; r < 4; ++r)
        bfv[j][r] = brow[qoff[r] + kt + j * 16 + lr];
    load_lds16(K + (size_t)(kt + srow) * 64 + schunk * 8, &lK[w * 512]);
    load_lds16(K + (size_t)(kt + 32 + srow) * 64 + schunk * 8, &lK[2048 + w * 512]);
    load_lds16(VT + (size_t)srow * 2048 + kt + schunk * 8, &lVT[w * 512]);
    load_lds16(VT + (size_t)(32 + srow) * 2048 + kt + schunk * 8, &lVT[2048 + w * 512]);
    __syncthreads();

    // S = Q K^T (16 q-rows x 64 keys per wave)
    f32x4 s4[4];
#pragma unroll
    for (int j = 0; j < 4; ++j) {
      f32x4 sj = {0.f, 0.f, 0.f, 0.f};
      const int krow = (j * 16 + lr) * 64;
      short8 kf0 = *(const short8*)&lK[krow + (lg ^ xr7) * 8];
      short8 kf1 = *(const short8*)&lK[krow + ((lg + 4) ^ xr7) * 8];
      sj = __builtin_amdgcn_mfma_f32_16x16x32_bf16(qf[0], kf0, sj, 0, 0, 0);
      sj = __builtin_amdgcn_mfma_f32_16x16x32_bf16(qf[1], kf1, sj, 0, 0, 0);
      s4[j] = sj;
    }
    // scale + bias + length mask; row max
    float rmax[4];
#pragma unroll
    for (int r = 0; r < 4; ++r) rmax[r] = -1e30f;
#pragma unroll
    for (int j = 0; j < 4; ++j) {
      const int key = kt + j * 16 + lr;
      const bool keep = key < len;
#pragma unroll
      for (int r = 0; r < 4; ++r) {
        float sv = s4[j][r] * 0.125f + bfv[j][r];
        sv = keep ? sv : -1e30f;
        s4[j][r] = sv;
        rmax[r] = fmaxf(rmax[r], sv);
      }
    }
#pragma unroll
    for (int d = 1; d < 16; d <<= 1)
#pragma unroll
      for (int r = 0; r < 4; ++r) rmax[r] = fmaxf(rmax[r], __shfl_xor(rmax[r], d, 64));
    // online softmax update
    float alpha[4];
#pragma unroll
    for (int r = 0; r < 4; ++r) {
      float mn = fmaxf(m[r], rmax[r]);
      alpha[r] = __expf(m[r] - mn);
      m[r] = mn;
    }
    float rsum[4] = {0.f, 0.f, 0.f, 0.f};
#pragma unroll
    for (int j = 0; j < 4; ++j)
#pragma unroll
      for (int r = 0; r < 4; ++r) {
        float p = __expf(s4[j][r] - m[r]);
        s4[j][r] = p;
        rsum[r] += p;
      }
#pragma unroll
    for (int d = 1; d < 16; d <<= 1)
#pragma unroll
      for (int r = 0; r < 4; ++r) rsum[r] += __shfl_xor(rsum[r], d, 64);
#pragma unroll
    for (int r = 0; r < 4; ++r) lsum[r] = lsum[r] * alpha[r] + rsum[r];
#pragma unroll
    for (int ni = 0; ni < 4; ++ni)
#pragma unroll
      for (int r = 0; r < 4; ++r) o[ni][r] *= alpha[r];
    // P (C-layout) -> LDS (swizzled) -> A-fragment layout for PV
#pragma unroll
    for (int j = 0; j < 4; ++j) {
      const int chunk = j * 2 + (lr >> 3);
#pragma unroll
      for (int r = 0; r < 4; ++r) {
        const int prow = lg * 4 + r;
        myP[prow * 64 + (chunk ^ (prow & 7)) * 8 + (l & 7)] = f2bf(s4[j][r]);
      }
    }
#pragma unroll
    for (int c = 0; c < 2; ++c) {
      short8 pf = *(const short8*)&myP[lr * 64 + ((c * 4 + lg) ^ xr7) * 8];
#pragma unroll
      for (int ni = 0; ni < 4; ++ni) {
        short8 vf = *(const short8*)&lVT[(ni * 16 + lr) * 64 + ((c * 4 + lg) ^ xr7) * 8];
        o[ni] = __builtin_amdgcn_mfma_f32_16x16x32_bf16(pf, vf, o[ni], 0, 0, 0);
      }
    }
  }
#pragma unroll
  for (int r = 0; r < 4; ++r) {
    float inv = 1.0f / lsum[r];
    const size_t orow = (size_t)b * 2048 + qt * 64 + w * 16 + lg * 4 + r;
#pragma unroll
    for (int ni = 0; ni < 4; ++ni)
      ctx[orow * 1024 + h * 64 + ni * 16 + lr] = f2bf(o[ni][r] * inv);
  }
}

// ---------------- GEMM2: out = ctx @ Wproj^T + bproj (fp32 out) ----------------
__global__ __launch_bounds__(256) void gemm_proj(const unsigned short* __restrict__ Cb,
                                                 const unsigned short* __restrict__ Wb,
                                                 const float* __restrict__ bproj,
                                                 float* __restrict__ out) {
  __shared__ unsigned short lA[128 * 32];
  __shared__ unsigned short lB[128 * 32];
  const int t = threadIdx.x;
  const int w = t >> 6, l = t & 63;
  const int wm = w >> 1, wn = w & 1;
  const int lr = l & 15, lg = l >> 4;
  const int row0 = blockIdx.x * 128, col0 = blockIdx.y * 128;
  const int srow = t >> 2;
  const int schunk = (t & 3) ^ (srow & 3);
  f32x4 acc[4][4] = {};
  for (int k0 = 0; k0 < 1024; k0 += 32) {
    __syncthreads();
    load_lds16(Cb + (size_t)(row0 + srow) * 1024 + k0 + schunk * 8, &lA[w * 512]);
    load_lds16(Cb + (size_t)(row0 + 64 + srow) * 1024 + k0 + schunk * 8, &lA[2048 + w * 512]);
    load_lds16(Wb + (size_t)(col0 + srow) * 1024 + k0 + schunk * 8, &lB[w * 512]);
    load_lds16(Wb + (size_t)(col0 + 64 + srow) * 1024 + k0 + schunk * 8, &lB[2048 + w * 512]);
    __syncthreads();
    short8 af[4], bf[4];
    const int rslot = (lg ^ (l & 3)) * 8;
#pragma unroll
    for (int mi = 0; mi < 4; ++mi)
      af[mi] = *(const short8*)&lA[(wm * 64 + mi * 16 + lr) * 32 + rslot];
#pragma unroll
    for (int ni = 0; ni < 4; ++ni)
      bf[ni] = *(const short8*)&lB[(wn * 64 + ni * 16 + lr) * 32 + rslot];
#pragma unroll
    for (int mi = 0; mi < 4; ++mi)
#pragma unroll
      for (int ni = 0; ni < 4; ++ni)
        acc[mi][ni] = __builtin_amdgcn_mfma_f32_16x16x32_bf16(af[mi], bf[ni], acc[mi][ni], 0, 0, 0);
  }
#pragma unroll
  for (int mi = 0; mi < 4; ++mi)
#pragma unroll
    for (int ni = 0; ni < 4; ++ni) {
      const int col = col0 + wn * 64 + ni * 16 + lr;
      const float bp = bproj[col];
#pragma unroll
      for (int r = 0; r < 4; ++r) {
        const int row = row0 + wm * 64 + mi * 16 + lg * 4 + r;
        out[(size_t)row * 1024 + col] = acc[mi][ni][r] + bp;
      }
    }
}

}  // namespace

extern "C" void kernel_launch(void* const* d_in, const int* in_sizes, int n_in,
                              void* d_out, int out_size, void* d_ws, size_t ws_size,
                              hipStream_t stream) {
  (void)in_sizes; (void)n_in; (void)out_size; (void)ws_size;
  const float* x        = (const float*)d_in[0];   // [2,2048,1024]
  const float* attnbias = (const float*)d_in[1];   // [2,2048,2048]
  const int*   mask     = (const int*)d_in[2];     // [2,2048]
  const float* Wqkv     = (const float*)d_in[3];   // [3072,1024]
  const float* Wproj    = (const float*)d_in[4];   // [1024,1024]
  const float* bproj    = (const float*)d_in[5];   // [1024]
  float* out = (float*)d_out;

  unsigned short* ws     = (unsigned short*)d_ws;
  unsigned short* xb     = ws;                  // 4194304 bf16
  unsigned short* wqkvb  = xb + 4194304;        // 3145728
  unsigned short* wprojb = wqkvb + 3145728;     // 1048576
  unsigned short* qws    = wprojb + 1048576;    // 4194304  [B*H][N][64]
  unsigned short* kws    = qws + 4194304;       // 4194304  [B*H][N][64]
  unsigned short* vTws   = kws + 4194304;       // 4194304  [B*H][64][N]
  unsigned short* ctxb   = vTws + 4194304;      // 4194304  [B][N][D]
  // total ws use: 48 MiB

  cvt_all<<<8192, 256, 0, stream>>>((const float4*)x, (const float4*)Wqkv,
                                    (const float4*)Wproj, (ushort4*)xb,
                                    (ushort4*)wqkvb, (ushort4*)wprojb);
  gemm_qkv<<<dim3(32, 24), 256, 0, stream>>>(xb, wqkvb, qws, kws, vTws);
  attn_fwd<<<dim3(32, 16, 2), 256, 0, stream>>>(qws, kws, vTws, attnbias, mask, ctxb);
  gemm_proj<<<dim3(32, 8), 256, 0, stream>>>(ctxb, wprojb, bproj, out);
}

// Round 3
// 187.006 us; speedup vs baseline: 1.1790x; 1.0223x over previous
//
#include <hip/hip_runtime.h>
#include <hip/hip_bf16.h>

// Problem constants: B=2, N=2048, D=1024, H=16, DH=64
namespace {

typedef short short8 __attribute__((ext_vector_type(8)));
typedef float f32x4 __attribute__((ext_vector_type(4)));

__device__ __forceinline__ unsigned short f2bf(float f) {
  union { __hip_bfloat16 h; unsigned short u; } cv;
  cv.h = __float2bfloat16(f);
  return cv.u;
}

// async global->LDS, 16B per lane. LDS base must be wave-uniform (lane l lands at +l*16B).
__device__ __forceinline__ void load_lds16(const void* g, void* l) {
  __builtin_amdgcn_global_load_lds((__attribute__((address_space(1))) void*)g,
                                   (__attribute__((address_space(3))) void*)l,
                                   16, 0, 0);
}

// ---------------- fp32 -> bf16 convert (all three tensors, one launch) ----------
__global__ __launch_bounds__(256) void cvt_all(const float4* __restrict__ x,
                                               const float4* __restrict__ wqkv,
                                               const float4* __restrict__ wproj,
                                               ushort4* __restrict__ xb,
                                               ushort4* __restrict__ wqkvb,
                                               ushort4* __restrict__ wprojb) {
  int i = blockIdx.x * 256 + threadIdx.x;
  const float4* src;
  ushort4* dst;
  int off;
  if (i < 1048576) { src = x; dst = xb; off = i; }
  else if (i < 1048576 + 786432) { src = wqkv; dst = wqkvb; off = i - 1048576; }
  else { src = wproj; dst = wprojb; off = i - (1048576 + 786432); }
  float4 f = src[off];
  ushort4 u;
  u.x = f2bf(f.x); u.y = f2bf(f.y); u.z = f2bf(f.z); u.w = f2bf(f.w);
  dst[off] = u;
}

// ---------------- GEMM1: qkv = x @ Wqkv^T, scatter to q/k/vT ----------------
// q stored pre-scaled by 0.125 (exact in bf16). q,k -> [B*H][N][64]; v -> [B*H][64][N]
__global__ __launch_bounds__(256) void gemm_qkv(const unsigned short* __restrict__ Xb,
                                                const unsigned short* __restrict__ Wb,
                                                unsigned short* __restrict__ qws,
                                                unsigned short* __restrict__ kws,
                                                unsigned short* __restrict__ vTws) {
  __shared__ unsigned short lA[128 * 32];
  __shared__ unsigned short lB[128 * 32];
  const int t = threadIdx.x;
  const int w = t >> 6, l = t & 63;
  const int wm = w >> 1, wn = w & 1;
  const int lr = l & 15, lg = l >> 4;
  const int row0 = blockIdx.x * 128, col0 = blockIdx.y * 128;
  const int srow = t >> 2;
  const int schunk = (t & 3) ^ (srow & 3);
  f32x4 acc[4][4] = {};
  for (int k0 = 0; k0 < 1024; k0 += 32) {
    __syncthreads();
    load_lds16(Xb + (size_t)(row0 + srow) * 1024 + k0 + schunk * 8, &lA[w * 512]);
    load_lds16(Xb + (size_t)(row0 + 64 + srow) * 1024 + k0 + schunk * 8, &lA[2048 + w * 512]);
    load_lds16(Wb + (size_t)(col0 + srow) * 1024 + k0 + schunk * 8, &lB[w * 512]);
    load_lds16(Wb + (size_t)(col0 + 64 + srow) * 1024 + k0 + schunk * 8, &lB[2048 + w * 512]);
    __syncthreads();
    short8 af[4], bf[4];
    const int rslot = (lg ^ (l & 3)) * 8;
#pragma unroll
    for (int mi = 0; mi < 4; ++mi)
      af[mi] = *(const short8*)&lA[(wm * 64 + mi * 16 + lr) * 32 + rslot];
#pragma unroll
    for (int ni = 0; ni < 4; ++ni)
      bf[ni] = *(const short8*)&lB[(wn * 64 + ni * 16 + lr) * 32 + rslot];
#pragma unroll
    for (int mi = 0; mi < 4; ++mi)
#pragma unroll
      for (int ni = 0; ni < 4; ++ni)
        acc[mi][ni] = __builtin_amdgcn_mfma_f32_16x16x32_bf16(af[mi], bf[ni], acc[mi][ni], 0, 0, 0);
  }
#pragma unroll
  for (int mi = 0; mi < 4; ++mi)
#pragma unroll
    for (int ni = 0; ni < 4; ++ni) {
      const int col = col0 + wn * 64 + ni * 16 + lr;
      const int s = col >> 10, rem = col & 1023;
      const int hh = rem >> 6, dh = rem & 63;
      const int row = row0 + wm * 64 + mi * 16 + lg * 4;
      const int bb = row >> 11, n = row & 2047;
      const size_t bh = (size_t)(bb * 16 + hh);
      if (s == 2) {
        ushort4 u4;
        u4.x = f2bf(acc[mi][ni][0]); u4.y = f2bf(acc[mi][ni][1]);
        u4.z = f2bf(acc[mi][ni][2]); u4.w = f2bf(acc[mi][ni][3]);
        *(ushort4*)&vTws[(bh * 64 + dh) * 2048 + n] = u4;
      } else if (s == 0) {
#pragma unroll
        for (int r = 0; r < 4; ++r)
          qws[(bh * 2048 + n + r) * 64 + dh] = f2bf(acc[mi][ni][r] * 0.125f);
      } else {
#pragma unroll
        for (int r = 0; r < 4; ++r)
          kws[(bh * 2048 + n + r) * 64 + dh] = f2bf(acc[mi][ni][r]);
      }
    }
}

// ---------------- Flash attention (S^T orientation) ----------------
// grid 2048 blocks of 128 thr (2 waves x 16 q-rows = 32-row q-tile). K-tile = 64 keys.
// mfma(K,Q) -> S^T: lane owns q-col = lr, keys = j*16 + lg*4 + r.
__global__ __launch_bounds__(128, 4) void attn_fwd(const unsigned short* __restrict__ qws,
                                                   const unsigned short* __restrict__ kws,
                                                   const unsigned short* __restrict__ vTws,
                                                   const float* __restrict__ bias,
                                                   const int* __restrict__ mask,
                                                   unsigned short* __restrict__ ctx) {
  __shared__ unsigned short lK[64 * 64];
  __shared__ unsigned short lVT[64 * 64];
  __shared__ unsigned short lP[2 * 16 * 64];
  __shared__ int lred[2];
  const int t = threadIdx.x, w = t >> 6, l = t & 63;
  const int lr = l & 15, lg = l >> 4;
  const int xr7 = lr & 7;

  // XCD-aware remap: (b, qt, h) order so one XCD's L2 keeps a 4MB bias slice
  // resident across all 16 heads.
  const int linear = blockIdx.x + 64 * blockIdx.y + 1024 * blockIdx.z;
  const int work = (linear >> 3) + (linear & 7) * 256;
  const int h = work & 15;
  const int qt = (work >> 4) & 63;
  const int b = work >> 10;

  const size_t bh = (size_t)(b * 16 + h);
  const unsigned short* Q = qws + bh * (2048 * 64);
  const unsigned short* K = kws + bh * (2048 * 64);
  const unsigned short* VT = vTws + bh * (64 * 2048);
  const float* brow = bias + (size_t)b * (2048 * 2048);

  // sequence length (prefix mask popcount)
  const int* mrow = mask + b * 2048;
  int scnt = 0;
  for (int i = t; i < 2048; i += 128) scnt += (mrow[i] != 0);
#pragma unroll
  for (int d = 1; d < 64; d <<= 1) scnt += __shfl_xor(scnt, d, 64);
  if (l == 0) lred[w] = scnt;
  __syncthreads();
  const int len = lred[0] + lred[1];
  const int nt = (len + 63) >> 6;

  // this lane's q (column of S^T)
  const int qv = qt * 32 + w * 16 + lr;
  short8 qf[2];
  qf[0] = *(const short8*)&Q[(size_t)qv * 64 + lg * 8];
  qf[1] = *(const short8*)&Q[(size_t)qv * 64 + 32 + lg * 8];
  const float* bq = brow + (size_t)qv * 2048;

  float m = -INFINITY, lsum = 0.f;
  f32x4 o[4] = {};
  unsigned short* myP = &lP[w * 1024];

  // staging: per wave, one inst covers 8 rows (64 lanes x 16B); chunk swizzle on source.
  const int sr = l >> 3;                 // row within 8-row stripe
  const int sc = (l & 7) ^ sr;           // inverse-swizzled source chunk
  const int wro = w * 8;                 // wave row offset

  for (int kt_i = 0; kt_i < nt; ++kt_i) {
    const int kt = kt_i << 6;
    __syncthreads();
    // bias: 4 x float4, issued first so latency hides under staging drain
    float4 b4[4];
#pragma unroll
    for (int j = 0; j < 4; ++j)
      b4[j] = *(const float4*)&bq[kt + j * 16 + lg * 4];
#pragma unroll
    for (int roff = 0; roff < 64; roff += 16) {
      load_lds16(K + (size_t)(kt + roff + wro + sr) * 64 + sc * 8, &lK[(roff + wro) * 64]);
      load_lds16(VT + (size_t)(roff + wro + sr) * 2048 + kt + sc * 8, &lVT[(roff + wro) * 64]);
    }
    __syncthreads();

    // S^T = K Q^T : 4 key-subtiles of 16
    f32x4 s4[4];
#pragma unroll
    for (int j = 0; j < 4; ++j) {
      f32x4 sj = {0.f, 0.f, 0.f, 0.f};
      const int krow = (j * 16 + lr) * 64;
      short8 kf0 = *(const short8*)&lK[krow + (lg ^ xr7) * 8];
      short8 kf1 = *(const short8*)&lK[krow + ((lg + 4) ^ xr7) * 8];
      sj = __builtin_amdgcn_mfma_f32_16x16x32_bf16(kf0, qf[0], sj, 0, 0, 0);
      sj = __builtin_amdgcn_mfma_f32_16x16x32_bf16(kf1, qf[1], sj, 0, 0, 0);
      s4[j] = sj;
    }
    // + bias (+ boundary mask)
    if (kt + 64 <= len) {
#pragma unroll
      for (int j = 0; j < 4; ++j) {
        s4[j][0] += b4[j].x; s4[j][1] += b4[j].y;
        s4[j][2] += b4[j].z; s4[j][3] += b4[j].w;
      }
    } else {
#pragma unroll
      for (int j = 0; j < 4; ++j) {
        const int kb = kt + j * 16 + lg * 4;
        const float* bp = &b4[j].x;
#pragma unroll
        for (int r = 0; r < 4; ++r)
          s4[j][r] = (kb + r < len) ? (s4[j][r] + bp[r]) : -1e30f;
      }
    }
    // softmax over keys: lane-local (16 values) + cross-lg reduce (2 shfl)
    float rl = -1e30f;
#pragma unroll
    for (int j = 0; j < 4; ++j)
#pragma unroll
      for (int r = 0; r < 4; ++r) rl = fmaxf(rl, s4[j][r]);
    rl = fmaxf(rl, __shfl_xor(rl, 16, 64));
    rl = fmaxf(rl, __shfl_xor(rl, 32, 64));
    const float mn = fmaxf(m, rl);
    const float alpha = __expf(m - mn);
    m = mn;
    float rs = 0.f;
#pragma unroll
    for (int j = 0; j < 4; ++j)
#pragma unroll
      for (int r = 0; r < 4; ++r) {
        float p = __expf(s4[j][r] - m);
        s4[j][r] = p;
        rs += p;
      }
    rs += __shfl_xor(rs, 16, 64);
    rs += __shfl_xor(rs, 32, 64);
    lsum = lsum * alpha + rs;
    // rescale o (rows q = lg*4+r): broadcast alpha from lane lr = lg*4+r
    float ash[4];
#pragma unroll
    for (int r = 0; r < 4; ++r) ash[r] = __shfl(alpha, lg * 4 + r, 16);
#pragma unroll
    for (int ni = 0; ni < 4; ++ni)
#pragma unroll
      for (int r = 0; r < 4; ++r) o[ni][r] *= ash[r];
    // P^T -> LDS (row = q = lr, 4 consecutive keys per write, swizzled)
#pragma unroll
    for (int j = 0; j < 4; ++j) {
      const int chunk = j * 2 + (lg >> 1);
      ushort4 pu;
      pu.x = f2bf(s4[j][0]); pu.y = f2bf(s4[j][1]);
      pu.z = f2bf(s4[j][2]); pu.w = f2bf(s4[j][3]);
      *(ushort4*)&myP[lr * 64 + (chunk ^ xr7) * 8 + (lg & 1) * 4] = pu;
    }
    // PV: o[q=lg*4+r][d=ni*16+lr]
#pragma unroll
    for (int c = 0; c < 2; ++c) {
      short8 pf = *(const short8*)&myP[lr * 64 + ((c * 4 + lg) ^ xr7) * 8];
#pragma unroll
      for (int ni = 0; ni < 4; ++ni) {
        short8 vf = *(const short8*)&lVT[(ni * 16 + lr) * 64 + ((c * 4 + lg) ^ xr7) * 8];
        o[ni] = __builtin_amdgcn_mfma_f32_16x16x32_bf16(pf, vf, o[ni], 0, 0, 0);
      }
    }
  }
  float linv[4];
#pragma unroll
  for (int r = 0; r < 4; ++r) linv[r] = 1.0f / __shfl(lsum, lg * 4 + r, 16);
#pragma unroll
  for (int r = 0; r < 4; ++r) {
    const size_t orow = (size_t)b * 2048 + qt * 32 + w * 16 + lg * 4 + r;
#pragma unroll
    for (int ni = 0; ni < 4; ++ni)
      ctx[orow * 1024 + h * 64 + ni * 16 + lr] = f2bf(o[ni][r] * linv[r]);
  }
}

// ---------------- GEMM2: out = ctx @ Wproj^T + bproj (fp32 out) ----------------
__global__ __launch_bounds__(256) void gemm_proj(const unsigned short* __restrict__ Cb,
                                                 const unsigned short* __restrict__ Wb,
                                                 const float* __restrict__ bproj,
                                                 float* __restrict__ out) {
  __shared__ unsigned short lA[128 * 32];
  __shared__ unsigned short lB[128 * 32];
  const int t = threadIdx.x;
  const int w = t >> 6, l = t & 63;
  const int wm = w >> 1, wn = w & 1;
  const int lr = l & 15, lg = l >> 4;
  const int row0 = blockIdx.x * 128, col0 = blockIdx.y * 128;
  const int srow = t >> 2;
  const int schunk = (t & 3) ^ (srow & 3);
  f32x4 acc[4][4] = {};
  for (int k0 = 0; k0 < 1024; k0 += 32) {
    __syncthreads();
    load_lds16(Cb + (size_t)(row0 + srow) * 1024 + k0 + schunk * 8, &lA[w * 512]);
    load_lds16(Cb + (size_t)(row0 + 64 + srow) * 1024 + k0 + schunk * 8, &lA[2048 + w * 512]);
    load_lds16(Wb + (size_t)(col0 + srow) * 1024 + k0 + schunk * 8, &lB[w * 512]);
    load_lds16(Wb + (size_t)(col0 + 64 + srow) * 1024 + k0 + schunk * 8, &lB[2048 + w * 512]);
    __syncthreads();
    short8 af[4], bf[4];
    const int rslot = (lg ^ (l & 3)) * 8;
#pragma unroll
    for (int mi = 0; mi < 4; ++mi)
      af[mi] = *(const short8*)&lA[(wm * 64 + mi * 16 + lr) * 32 + rslot];
#pragma unroll
    for (int ni = 0; ni < 4; ++ni)
      bf[ni] = *(const short8*)&lB[(wn * 64 + ni * 16 + lr) * 32 + rslot];
#pragma unroll
    for (int mi = 0; mi < 4; ++mi)
#pragma unroll
      for (int ni = 0; ni < 4; ++ni)
        acc[mi][ni] = __builtin_amdgcn_mfma_f32_16x16x32_bf16(af[mi], bf[ni], acc[mi][ni], 0, 0, 0);
  }
#pragma unroll
  for (int mi = 0; mi < 4; ++mi)
#pragma unroll
    for (int ni = 0; ni < 4; ++ni) {
      const int col = col0 + wn * 64 + ni * 16 + lr;
      const float bp = bproj[col];
#pragma unroll
      for (int r = 0; r < 4; ++r) {
        const int row = row0 + wm * 64 + mi * 16 + lg * 4 + r;
        out[(size_t)row * 1024 + col] = acc[mi][ni][r] + bp;
      }
    }
}

}  // namespace

extern "C" void kernel_launch(void* const* d_in, const int* in_sizes, int n_in,
                              void* d_out, int out_size, void* d_ws, size_t ws_size,
                              hipStream_t stream) {
  (void)in_sizes; (void)n_in; (void)out_size; (void)ws_size;
  const float* x        = (const float*)d_in[0];   // [2,2048,1024]
  const float* attnbias = (const float*)d_in[1];   // [2,2048,2048]
  const int*   mask     = (const int*)d_in[2];     // [2,2048]
  const float* Wqkv     = (const float*)d_in[3];   // [3072,1024]
  const float* Wproj    = (const float*)d_in[4];   // [1024,1024]
  const float* bproj    = (const float*)d_in[5];   // [1024]
  float* out = (float*)d_out;

  unsigned short* ws     = (unsigned short*)d_ws;
  unsigned short* xb     = ws;                  // 4194304 bf16
  unsigned short* wqkvb  = xb + 4194304;        // 3145728
  unsigned short* wprojb = wqkvb + 3145728;     // 1048576
  unsigned short* qws    = wprojb + 1048576;    // 4194304  [B*H][N][64] (pre-scaled)
  unsigned short* kws    = qws + 4194304;       // 4194304  [B*H][N][64]
  unsigned short* vTws   = kws + 4194304;       // 4194304  [B*H][64][N]
  unsigned short* ctxb   = vTws + 4194304;      // 4194304  [B][N][D]

  cvt_all<<<8192, 256, 0, stream>>>((const float4*)x, (const float4*)Wqkv,
                                    (const float4*)Wproj, (ushort4*)xb,
                                    (ushort4*)wqkvb, (ushort4*)wprojb);
  gemm_qkv<<<dim3(32, 24), 256, 0, stream>>>(xb, wqkvb, qws, kws, vTws);
  attn_fwd<<<dim3(64, 16, 2), 128, 0, stream>>>(qws, kws, vTws, attnbias, mask, ctxb);
  gemm_proj<<<dim3(32, 8), 256, 0, stream>>>(ctxb, wprojb, bproj, out);
}

// Round 4
// 156.121 us; speedup vs baseline: 1.4122x; 1.1978x over previous
//
#include <hip/hip_runtime.h>
#include <hip/hip_bf16.h>

// Problem constants: B=2, N=2048, D=1024, H=16, DH=64
namespace {

typedef short short8 __attribute__((ext_vector_type(8)));
typedef float f32x4 __attribute__((ext_vector_type(4)));

__device__ __forceinline__ unsigned short f2bf(float f) {
  union { __hip_bfloat16 h; unsigned short u; } cv;
  cv.h = __float2bfloat16(f);
  return cv.u;
}

__device__ __forceinline__ unsigned cvt_pk_bf16(float lo, float hi) {
  unsigned r;
  asm("v_cvt_pk_bf16_f32 %0, %1, %2" : "=v"(r) : "v"(lo), "v"(hi));
  return r;
}

// async global->LDS, 16B per lane. LDS base must be wave-uniform (lane l lands at +l*16B).
__device__ __forceinline__ void load_lds16(const void* g, void* l) {
  __builtin_amdgcn_global_load_lds((__attribute__((address_space(1))) void*)g,
                                   (__attribute__((address_space(3))) void*)l,
                                   16, 0, 0);
}

// key permutation within a 64-tile: LDS K-row rho holds original key pi64(rho).
// Chosen so P-redistribution for PV is {own lane} + {lane^32 partner} only.
__device__ __forceinline__ int pi64(int rho) {
  const int c32 = rho & 32;
  const int o = (rho >> 4) & 1;
  const int g = (rho >> 2) & 3;
  const int s = rho & 3;
  return c32 + (o ? (((g ^ 2) << 3) + 4 + s) : ((g << 3) + s));
}

// ---------------- fp32 -> bf16 convert (all three tensors, one launch) ----------
__global__ __launch_bounds__(256) void cvt_all(const float4* __restrict__ x,
                                               const float4* __restrict__ wqkv,
                                               const float4* __restrict__ wproj,
                                               ushort4* __restrict__ xb,
                                               ushort4* __restrict__ wqkvb,
                                               ushort4* __restrict__ wprojb) {
  int i = blockIdx.x * 256 + threadIdx.x;
  const float4* src;
  ushort4* dst;
  int off;
  if (i < 1048576) { src = x; dst = xb; off = i; }
  else if (i < 1048576 + 786432) { src = wqkv; dst = wqkvb; off = i - 1048576; }
  else { src = wproj; dst = wprojb; off = i - (1048576 + 786432); }
  float4 f = src[off];
  ushort4 u;
  u.x = f2bf(f.x); u.y = f2bf(f.y); u.z = f2bf(f.z); u.w = f2bf(f.w);
  dst[off] = u;
}

// ---------------- GEMM1: qkv = x @ Wqkv^T, scatter to q/k/vT ----------------
// q stored pre-scaled by 0.125 (exact in bf16). q,k -> [B*H][N][64]; v -> [B*H][64][N]
__global__ __launch_bounds__(256) void gemm_qkv(const unsigned short* __restrict__ Xb,
                                                const unsigned short* __restrict__ Wb,
                                                unsigned short* __restrict__ qws,
                                                unsigned short* __restrict__ kws,
                                                unsigned short* __restrict__ vTws) {
  __shared__ unsigned short lA[128 * 32];
  __shared__ unsigned short lB[128 * 32];
  const int t = threadIdx.x;
  const int w = t >> 6, l = t & 63;
  const int wm = w >> 1, wn = w & 1;
  const int lr = l & 15, lg = l >> 4;
  const int row0 = blockIdx.x * 128, col0 = blockIdx.y * 128;
  const int srow = t >> 2;
  const int schunk = (t & 3) ^ (srow & 3);
  f32x4 acc[4][4] = {};
  for (int k0 = 0; k0 < 1024; k0 += 32) {
    __syncthreads();
    load_lds16(Xb + (size_t)(row0 + srow) * 1024 + k0 + schunk * 8, &lA[w * 512]);
    load_lds16(Xb + (size_t)(row0 + 64 + srow) * 1024 + k0 + schunk * 8, &lA[2048 + w * 512]);
    load_lds16(Wb + (size_t)(col0 + srow) * 1024 + k0 + schunk * 8, &lB[w * 512]);
    load_lds16(Wb + (size_t)(col0 + 64 + srow) * 1024 + k0 + schunk * 8, &lB[2048 + w * 512]);
    __syncthreads();
    short8 af[4], bf[4];
    const int rslot = (lg ^ (l & 3)) * 8;
#pragma unroll
    for (int mi = 0; mi < 4; ++mi)
      af[mi] = *(const short8*)&lA[(wm * 64 + mi * 16 + lr) * 32 + rslot];
#pragma unroll
    for (int ni = 0; ni < 4; ++ni)
      bf[ni] = *(const short8*)&lB[(wn * 64 + ni * 16 + lr) * 32 + rslot];
#pragma unroll
    for (int mi = 0; mi < 4; ++mi)
#pragma unroll
      for (int ni = 0; ni < 4; ++ni)
        acc[mi][ni] = __builtin_amdgcn_mfma_f32_16x16x32_bf16(af[mi], bf[ni], acc[mi][ni], 0, 0, 0);
  }
#pragma unroll
  for (int mi = 0; mi < 4; ++mi)
#pragma unroll
    for (int ni = 0; ni < 4; ++ni) {
      const int col = col0 + wn * 64 + ni * 16 + lr;
      const int s = col >> 10, rem = col & 1023;
      const int hh = rem >> 6, dh = rem & 63;
      const int row = row0 + wm * 64 + mi * 16 + lg * 4;
      const int bb = row >> 11, n = row & 2047;
      const size_t bh = (size_t)(bb * 16 + hh);
      if (s == 2) {
        ushort4 u4;
        u4.x = f2bf(acc[mi][ni][0]); u4.y = f2bf(acc[mi][ni][1]);
        u4.z = f2bf(acc[mi][ni][2]); u4.w = f2bf(acc[mi][ni][3]);
        *(ushort4*)&vTws[(bh * 64 + dh) * 2048 + n] = u4;
      } else if (s == 0) {
#pragma unroll
        for (int r = 0; r < 4; ++r)
          qws[(bh * 2048 + n + r) * 64 + dh] = f2bf(acc[mi][ni][r] * 0.125f);
      } else {
#pragma unroll
        for (int r = 0; r < 4; ++r)
          kws[(bh * 2048 + n + r) * 64 + dh] = f2bf(acc[mi][ni][r]);
      }
    }
}

// ---------------- Flash attention (S^T, double-buffered, reg-redistributed P) ----
// grid 1024 x 256 thr (4 waves x 16 q-rows = 64-row q-tile). K-tile = 64 keys.
__global__ __launch_bounds__(256, 4) void attn_fwd(const unsigned short* __restrict__ qws,
                                                   const unsigned short* __restrict__ kws,
                                                   const unsigned short* __restrict__ vTws,
                                                   const float* __restrict__ bias,
                                                   const int* __restrict__ mask,
                                                   unsigned short* __restrict__ ctx) {
  __shared__ unsigned short lK[2][64 * 64];
  __shared__ unsigned short lVT[2][64 * 64];
  __shared__ int lred[4];
  const int t = threadIdx.x, w = t >> 6, l = t & 63;
  const int lr = l & 15, lg = l >> 4;
  const int xr7 = lr & 7;

  // XCD-grouped mapping: 16 heads of the same (b,qt) share one XCD's L2 bias slice.
  const int lin = blockIdx.x;
  const int g8 = lin & 7;
  const int k7 = lin >> 3;          // 0..127
  const int h = k7 & 15;
  const int gg = g8 + (k7 >> 4) * 8;  // 0..63
  const int qt = gg >> 1;
  const int b = gg & 1;

  const size_t bh = (size_t)(b * 16 + h);
  const unsigned short* Q = qws + bh * (2048 * 64);
  const unsigned short* K = kws + bh * (2048 * 64);
  const unsigned short* VT = vTws + bh * (64 * 2048);
  const float* brow = bias + (size_t)b * (2048 * 2048);

  // sequence length (prefix mask popcount)
  const int* mrow = mask + b * 2048;
  int scnt = 0;
  for (int i = t; i < 2048; i += 256) scnt += (mrow[i] != 0);
#pragma unroll
  for (int d = 1; d < 64; d <<= 1) scnt += __shfl_xor(scnt, d, 64);
  if (l == 0) lred[w] = scnt;
  __syncthreads();
  const int len = lred[0] + lred[1] + lred[2] + lred[3];
  const int nt = (len + 63) >> 6;

  // this lane's q (column of S^T); q pre-scaled by 1/8 in gemm_qkv
  const int qv = qt * 64 + w * 16 + lr;
  short8 qf[2];
  qf[0] = *(const short8*)&Q[(size_t)qv * 64 + lg * 8];
  qf[1] = *(const short8*)&Q[(size_t)qv * 64 + 32 + lg * 8];
  const float* bq = brow + (size_t)qv * 2048;

  // permuted bias column offsets for p[j][r] -> orig key kt + boffs[j] + r
  const int be = lg * 8, bo = ((lg ^ 2) * 8) + 4;
  const int boffs[4] = {be, bo, 32 + be, 32 + bo};

  float m = -INFINITY, lsum = 0.f;
  f32x4 o[4] = {};

  // staging geometry: wave w stages rows w*16 + u*8 + sr (u=0,1) of both K and VT
  const int sr = l >> 3;
  const int sc7 = l & 7;

  // prologue: stage tile 0, bias tile 0
  float4 b4[4];
#pragma unroll
  for (int u = 0; u < 2; ++u) {
    const int row = w * 16 + u * 8 + sr;
    const int srcc = (sc7 ^ sr) * 8;
    load_lds16(K + (size_t)pi64(row) * 64 + srcc, &lK[0][(w * 16 + u * 8) * 64]);
    load_lds16(VT + (size_t)row * 2048 + srcc, &lVT[0][(w * 16 + u * 8) * 64]);
  }
#pragma unroll
  for (int j = 0; j < 4; ++j) b4[j] = *(const float4*)&bq[boffs[j]];
  __syncthreads();

  for (int ti = 0;;) {
    const int cur = ti & 1;
    const int kt = ti << 6;
    const bool notlast = (ti + 1 < nt);
    float4 b4n[4];
    if (notlast) {
      const int ktn = kt + 64;
#pragma unroll
      for (int u = 0; u < 2; ++u) {
        const int row = w * 16 + u * 8 + sr;
        const int srcc = (sc7 ^ sr) * 8;
        load_lds16(K + (size_t)(ktn + pi64(row)) * 64 + srcc, &lK[cur ^ 1][(w * 16 + u * 8) * 64]);
        load_lds16(VT + (size_t)row * 2048 + ktn + srcc, &lVT[cur ^ 1][(w * 16 + u * 8) * 64]);
      }
#pragma unroll
      for (int j = 0; j < 4; ++j) b4n[j] = *(const float4*)&bq[ktn + boffs[j]];
    }

    // S^T = K Q^T : p[j][r] = score of orig key kt + boffs[j] + r, q = lr
    f32x4 s4[4];
#pragma unroll
    for (int j = 0; j < 4; ++j) {
      f32x4 sj = {0.f, 0.f, 0.f, 0.f};
      const int krow = (j * 16 + lr) * 64;
      short8 kf0 = *(const short8*)&lK[cur][krow + (lg ^ xr7) * 8];
      short8 kf1 = *(const short8*)&lK[cur][krow + ((lg + 4) ^ xr7) * 8];
      sj = __builtin_amdgcn_mfma_f32_16x16x32_bf16(kf0, qf[0], sj, 0, 0, 0);
      sj = __builtin_amdgcn_mfma_f32_16x16x32_bf16(kf1, qf[1], sj, 0, 0, 0);
      s4[j] = sj;
    }
    // + bias (+ boundary mask over original key index)
    if (kt + 64 <= len) {
#pragma unroll
      for (int j = 0; j < 4; ++j) {
        s4[j][0] += b4[j].x; s4[j][1] += b4[j].y;
        s4[j][2] += b4[j].z; s4[j][3] += b4[j].w;
      }
    } else {
#pragma unroll
      for (int j = 0; j < 4; ++j) {
        const int kb = kt + boffs[j];
        const float* bp = &b4[j].x;
#pragma unroll
        for (int r = 0; r < 4; ++r)
          s4[j][r] = (kb + r < len) ? (s4[j][r] + bp[r]) : -1e30f;
      }
    }
    // softmax over keys: 16 lane-local + 2 shfl (uniform across lg after)
    float rl = -1e30f;
#pragma unroll
    for (int j = 0; j < 4; ++j)
#pragma unroll
      for (int r = 0; r < 4; ++r) rl = fmaxf(rl, s4[j][r]);
    rl = fmaxf(rl, __shfl_xor(rl, 16, 64));
    rl = fmaxf(rl, __shfl_xor(rl, 32, 64));
    const float mn = fmaxf(m, rl);
    const float alpha = __expf(m - mn);
    m = mn;
    float rs = 0.f;
#pragma unroll
    for (int j = 0; j < 4; ++j)
#pragma unroll
      for (int r = 0; r < 4; ++r) {
        float p = __expf(s4[j][r] - m);
        s4[j][r] = p;
        rs += p;
      }
    rs += __shfl_xor(rs, 16, 64);
    rs += __shfl_xor(rs, 32, 64);
    lsum = lsum * alpha + rs;
    // rescale o (rows q = lg*4+r): broadcast alpha from lane lr = lg*4+r
    float ash[4];
#pragma unroll
    for (int r = 0; r < 4; ++r) ash[r] = __shfl(alpha, lg * 4 + r, 16);
#pragma unroll
    for (int ni = 0; ni < 4; ++ni)
#pragma unroll
      for (int r = 0; r < 4; ++r) o[ni][r] *= ash[r];

    // P redistribution in-register: pack to bf16 pairs, partner = lane^32
    unsigned wj0[4], wj1[4];
#pragma unroll
    for (int j = 0; j < 4; ++j) {
      wj0[j] = cvt_pk_bf16(s4[j][0], s4[j][1]);
      wj1[j] = cvt_pk_bf16(s4[j][2], s4[j][3]);
    }
#pragma unroll
    for (int c = 0; c < 2; ++c) {
      union { unsigned u[4]; short8 s8; } pu;
      pu.u[0] = wj0[2 * c];
      pu.u[1] = wj1[2 * c];
      pu.u[2] = (unsigned)__shfl_xor((int)wj0[2 * c + 1], 32, 64);
      pu.u[3] = (unsigned)__shfl_xor((int)wj1[2 * c + 1], 32, 64);
#pragma unroll
      for (int ni = 0; ni < 4; ++ni) {
        short8 vf = *(const short8*)&lVT[cur][(ni * 16 + lr) * 64 + ((c * 4 + lg) ^ xr7) * 8];
        o[ni] = __builtin_amdgcn_mfma_f32_16x16x32_bf16(pu.s8, vf, o[ni], 0, 0, 0);
      }
    }
    if (!notlast) break;
#pragma unroll
    for (int j = 0; j < 4; ++j) b4[j] = b4n[j];
    __syncthreads();
    ++ti;
  }
  float linv[4];
#pragma unroll
  for (int r = 0; r < 4; ++r) linv[r] = 1.0f / __shfl(lsum, lg * 4 + r, 16);
#pragma unroll
  for (int r = 0; r < 4; ++r) {
    const size_t orow = (size_t)b * 2048 + qt * 64 + w * 16 + lg * 4 + r;
#pragma unroll
    for (int ni = 0; ni < 4; ++ni)
      ctx[orow * 1024 + h * 64 + ni * 16 + lr] = f2bf(o[ni][r] * linv[r]);
  }
}

// ---------------- GEMM2: out = ctx @ Wproj^T + bproj (fp32 out) ----------------
__global__ __launch_bounds__(256) void gemm_proj(const unsigned short* __restrict__ Cb,
                                                 const unsigned short* __restrict__ Wb,
                                                 const float* __restrict__ bproj,
                                                 float* __restrict__ out) {
  __shared__ unsigned short lA[128 * 32];
  __shared__ unsigned short lB[128 * 32];
  const int t = threadIdx.x;
  const int w = t >> 6, l = t & 63;
  const int wm = w >> 1, wn = w & 1;
  const int lr = l & 15, lg = l >> 4;
  const int row0 = blockIdx.x * 128, col0 = blockIdx.y * 128;
  const int srow = t >> 2;
  const int schunk = (t & 3) ^ (srow & 3);
  f32x4 acc[4][4] = {};
  for (int k0 = 0; k0 < 1024; k0 += 32) {
    __syncthreads();
    load_lds16(Cb + (size_t)(row0 + srow) * 1024 + k0 + schunk * 8, &lA[w * 512]);
    load_lds16(Cb + (size_t)(row0 + 64 + srow) * 1024 + k0 + schunk * 8, &lA[2048 + w * 512]);
    load_lds16(Wb + (size_t)(col0 + srow) * 1024 + k0 + schunk * 8, &lB[w * 512]);
    load_lds16(Wb + (size_t)(col0 + 64 + srow) * 1024 + k0 + schunk * 8, &lB[2048 + w * 512]);
    __syncthreads();
    short8 af[4], bf[4];
    const int rslot = (lg ^ (l & 3)) * 8;
#pragma unroll
    for (int mi = 0; mi < 4; ++mi)
      af[mi] = *(const short8*)&lA[(wm * 64 + mi * 16 + lr) * 32 + rslot];
#pragma unroll
    for (int ni = 0; ni < 4; ++ni)
      bf[ni] = *(const short8*)&lB[(wn * 64 + ni * 16 + lr) * 32 + rslot];
#pragma unroll
    for (int mi = 0; mi < 4; ++mi)
#pragma unroll
      for (int ni = 0; ni < 4; ++ni)
        acc[mi][ni] = __builtin_amdgcn_mfma_f32_16x16x32_bf16(af[mi], bf[ni], acc[mi][ni], 0, 0, 0);
  }
#pragma unroll
  for (int mi = 0; mi < 4; ++mi)
#pragma unroll
    for (int ni = 0; ni < 4; ++ni) {
      const int col = col0 + wn * 64 + ni * 16 + lr;
      const float bp = bproj[col];
#pragma unroll
      for (int r = 0; r < 4; ++r) {
        const int row = row0 + wm * 64 + mi * 16 + lg * 4 + r;
        out[(size_t)row * 1024 + col] = acc[mi][ni][r] + bp;
      }
    }
}

}  // namespace

extern "C" void kernel_launch(void* const* d_in, const int* in_sizes, int n_in,
                              void* d_out, int out_size, void* d_ws, size_t ws_size,
                              hipStream_t stream) {
  (void)in_sizes; (void)n_in; (void)out_size; (void)ws_size;
  const float* x        = (const float*)d_in[0];   // [2,2048,1024]
  const float* attnbias = (const float*)d_in[1];   // [2,2048,2048]
  const int*   mask     = (const int*)d_in[2];     // [2,2048]
  const float* Wqkv     = (const float*)d_in[3];   // [3072,1024]
  const float* Wproj    = (const float*)d_in[4];   // [1024,1024]
  const float* bproj    = (const float*)d_in[5];   // [1024]
  float* out = (float*)d_out;

  unsigned short* ws     = (unsigned short*)d_ws;
  unsigned short* xb     = ws;                  // 4194304 bf16
  unsigned short* wqkvb  = xb + 4194304;        // 3145728
  unsigned short* wprojb = wqkvb + 3145728;     // 1048576
  unsigned short* qws    = wprojb + 1048576;    // 4194304  [B*H][N][64] (pre-scaled)
  unsigned short* kws    = qws + 4194304;       // 4194304  [B*H][N][64]
  unsigned short* vTws   = kws + 4194304;       // 4194304  [B*H][64][N]
  unsigned short* ctxb   = vTws + 4194304;      // 4194304  [B][N][D]

  cvt_all<<<8192, 256, 0, stream>>>((const float4*)x, (const float4*)Wqkv,
                                    (const float4*)Wproj, (ushort4*)xb,
                                    (ushort4*)wqkvb, (ushort4*)wprojb);
  gemm_qkv<<<dim3(32, 24), 256, 0, stream>>>(xb, wqkvb, qws, kws, vTws);
  attn_fwd<<<1024, 256, 0, stream>>>(qws, kws, vTws, attnbias, mask, ctxb);
  gemm_proj<<<dim3(32, 8), 256, 0, stream>>>(ctxb, wprojb, bproj, out);
}